// Round 17
// baseline (330.974 us; speedup 1.0000x reference)
//
#include <hip/hip_runtime.h>

// ---------------------------------------------------------------------------
// PolicyNet fused forward, MFMA bf16x3 step loop, MI355X.
// Round 17: (1) FIX latent R16 race: S1 split into {MFMA->gacc regs} |
// barrier | {pointwise h/c write} — A-frag reads of h_old now provably
// precede h_new writes. Gates still never touch LDS. (2) S7(st-1) merged
// into next step's phase A (disjoint LDS: S7 reads VBUF att, S1 reads H/C),
// stores overlap gates MFMA; final S7 after the loop. (3) S7 balanced as
// 20 half-jobs over 8 waves. Numerics identical (absmax 4.88e-4).
// ---------------------------------------------------------------------------

#define RF(x) __builtin_amdgcn_readfirstlane(x)

constexpr int BATCH = 16384;

typedef short bf16x8 __attribute__((ext_vector_type(8)));
typedef float f32x4  __attribute__((ext_vector_type(4)));

// ---- workspace layout (dwords) ----
constexpr int WS_FC1T = 0;       // [152][64]  fc1_w^T (zero-padded K)
constexpr int WS_FC2T = 9728;    // [64][64]
constexpr int WS_FC3T = 13824;   // [64][12]   (cols 10,11 zero)
constexpr int WS_H0T  = 14592;   // [64][64]
constexpr int WS_C0T  = 18688;   // [64][64]
constexpr int WS_WHHT = 22784;   // [64][256]  whh^T, col = gate*64+j (i,f,g,o)
constexpr int WS_GB   = 39168;   // [256]      bih+bhh
constexpr int WS_W2   = 39424;   // [5][64][64]   emb_w @ predfc_w_t
constexpr int WS_B2   = 59904;   // [5][64]
constexpr int WS_W3QK = 60224;   // [4][64][160]  per head: [k][t*32 + (q0..15|k16..31)]
constexpr int WS_W3V  = 101184;  // [64][320]     [k][t*64 + h*16 + d]
constexpr int WS_B3QK = 121664;  // [4][160]
constexpr int WS_B3V  = 122304;  // [320]
constexpr int WS_W4T  = 122624;  // [64][152]  (unemb_w @ attn_out_w)^T
constexpr int WS_B4   = 132352;  // [152]
constexpr int WS_FC3B = 132504;  // [12]
constexpr int WS_W4F  = 132520;  // [10n][2s][2split][64l][4dw] bf16 B-frags (S7)
constexpr int WS_GF   = 142760;  // gates frags: 16 n-tiles  (16384 dw)
constexpr int WS_VF   = 159144;  // v frags:     20 n-tiles  (20480 dw)
constexpr int WS_QKF  = 179624;  // qk frags: 4 heads x 10 n (40960 dw)
constexpr int WS_TOTAL= 220584;  // dwords (~882 KB)

// ---- LDS layout (dwords), 32-row tile ----
constexpr int VSTR     = 324;    // VBUF [32][324]: v / att (x, h2 alias)
constexpr int QK_OFF   = 10368;  // [32][164]  (h1 aliases)
constexpr int QKSTR    = 164;
constexpr int H_OFF    = 15616;  // [32][68]
constexpr int C_OFF    = 17792;  // [32][68]
constexpr int HSTR     = 68;
constexpr int XSTR     = 156;    // x staged at VBUF offset 0
constexpr int H1_OFF   = QK_OFF;
constexpr int H2_OFF   = 4992;   // after x within VBUF
constexpr int LDS_DW   = 19968;  // 79872 bytes -> 2 blocks/CU

// ---------------------------------------------------------------------------
__device__ __forceinline__ unsigned rnbf16_bits(float f) {
    unsigned u = __float_as_uint(f);
    return (u + 0x7FFFu + ((u >> 16) & 1u)) >> 16;   // round-nearest-even
}

// ---------------------------------------------------------------------------
// precompute kernel 1: transposes + W2/b2 + W4/b4 + misc biases
// ---------------------------------------------------------------------------
__global__ void k_pre1(const float* __restrict__ fc1_w, const float* __restrict__ fc2_w,
                       const float* __restrict__ fc3_w, const float* __restrict__ fc3_b,
                       const float* __restrict__ h0_w,  const float* __restrict__ c0_w,
                       const float* __restrict__ whh,   const float* __restrict__ bih,
                       const float* __restrict__ bhh,
                       const float* __restrict__ predfc_w, const float* __restrict__ predfc_b,
                       const float* __restrict__ emb_w,    const float* __restrict__ emb_b,
                       const float* __restrict__ aow, const float* __restrict__ aob,
                       const float* __restrict__ unw, const float* __restrict__ unb,
                       float* ws)
{
    int idx = blockIdx.x * 256 + threadIdx.x;
    if (idx < 9728) { int k = idx / 64, c = idx & 63;
        ws[WS_FC1T + idx] = (k < 150) ? fc1_w[c * 150 + k] : 0.f; return; }
    idx -= 9728;
    if (idx < 4096) { int k = idx >> 6, c = idx & 63; ws[WS_FC2T + idx] = fc2_w[c * 64 + k]; return; }
    idx -= 4096;
    if (idx < 768)  { int k = idx / 12, c = idx % 12;
        ws[WS_FC3T + idx] = (c < 10) ? fc3_w[c * 64 + k] : 0.f; return; }
    idx -= 768;
    if (idx < 4096) { int k = idx >> 6, c = idx & 63; ws[WS_H0T + idx] = h0_w[c * 64 + k]; return; }
    idx -= 4096;
    if (idx < 4096) { int k = idx >> 6, c = idx & 63; ws[WS_C0T + idx] = c0_w[c * 64 + k]; return; }
    idx -= 4096;
    if (idx < 16384){ int k = idx >> 8, c = idx & 255; ws[WS_WHHT + idx] = whh[c * 64 + k]; return; }
    idx -= 16384;
    if (idx < 256)  { ws[WS_GB + idx] = bih[idx] + bhh[idx]; return; }
    idx -= 256;
    if (idx < 20480){ int t = idx / 4096, r = idx & 4095, kk = r >> 6, j = r & 63;
        float s = 0.f;
        for (int m = 0; m < 150; ++m)
            s = fmaf(emb_w[kk * 150 + m], predfc_w[(t * 150 + m) * 64 + j], s);
        ws[WS_W2 + idx] = s; return; }
    idx -= 20480;
    if (idx < 320)  { int t = idx / 64, kk = idx & 63;
        float s = emb_b[kk];
        for (int m = 0; m < 150; ++m)
            s = fmaf(emb_w[kk * 150 + m], predfc_b[t * 150 + m], s);
        ws[WS_B2 + idx] = s; return; }
    idx -= 320;
    if (idx < 9728) { int k = idx / 152, ss = idx % 152;
        float v = 0.f;
        if (ss < 150) { float a = 0.f;
            for (int kk = 0; kk < 64; ++kk) a = fmaf(unw[ss * 64 + kk], aow[kk * 64 + k], a);
            v = a; }
        ws[WS_W4T + idx] = v; return; }
    idx -= 9728;
    if (idx < 152)  { float v = 0.f;
        if (idx < 150) { float a = unb[idx];
            for (int kk = 0; kk < 64; ++kk) a = fmaf(unw[idx * 64 + kk], aob[kk], a);
            v = a; }
        ws[WS_B4 + idx] = v; return; }
    idx -= 152;
    if (idx < 12)   { ws[WS_FC3B + idx] = (idx < 10) ? fc3_b[idx] : 0.f; return; }
}
constexpr int PRE1_ITEMS = 70116;

// ---------------------------------------------------------------------------
// precompute kernel 2: W3 = attn_in_w @ W2  (q rows scaled by 0.25), b3
// ---------------------------------------------------------------------------
__global__ void k_pre2(const float* __restrict__ aiw, const float* __restrict__ aib,
                       float* ws)
{
    int idx = blockIdx.x * 256 + threadIdx.x;
    const float* W2 = ws + WS_W2;
    const float* b2 = ws + WS_B2;
    if (idx < 40960) {
        int h = idx / 10240, r = idx % 10240, k = r / 160, c = r % 160;
        int t = c / 32, rr = c % 32;
        int row; float scale;
        if (rr < 16) { row = h * 16 + rr;            scale = 0.25f; }
        else         { row = 64 + h * 16 + (rr - 16); scale = 1.f;  }
        float s = 0.f;
        for (int kk = 0; kk < 64; ++kk)
            s = fmaf(aiw[row * 64 + kk], W2[t * 4096 + kk * 64 + k], s);
        ws[WS_W3QK + idx] = s * scale; return;
    }
    idx -= 40960;
    if (idx < 20480) {
        int k = idx / 320, c = idx % 320, t = c >> 6, r3 = c & 63;
        int row = 128 + r3;
        float s = 0.f;
        for (int kk = 0; kk < 64; ++kk)
            s = fmaf(aiw[row * 64 + kk], W2[t * 4096 + kk * 64 + k], s);
        ws[WS_W3V + idx] = s; return;
    }
    idx -= 20480;
    if (idx < 640) {
        int h = idx / 160, c = idx % 160, t = c / 32, rr = c % 32;
        int row; float scale;
        if (rr < 16) { row = h * 16 + rr;            scale = 0.25f; }
        else         { row = 64 + h * 16 + (rr - 16); scale = 1.f;  }
        float s = aib[row];
        for (int kk = 0; kk < 64; ++kk)
            s = fmaf(aiw[row * 64 + kk], b2[t * 64 + kk], s);
        ws[WS_B3QK + idx] = s * scale; return;
    }
    idx -= 640;
    if (idx < 320) {
        int t = idx >> 6, r3 = idx & 63, row = 128 + r3;
        float s = aib[row];
        for (int kk = 0; kk < 64; ++kk)
            s = fmaf(aiw[row * 64 + kk], b2[t * 64 + kk], s);
        ws[WS_B3V + idx] = s; return;
    }
}
constexpr int PRE2_ITEMS = 62400;

// ---------------------------------------------------------------------------
// precompute kernel 3: W4 bf16 hi/lo B-fragment pack (validated R4).
// ---------------------------------------------------------------------------
__global__ void k_pre3(float* ws)
{
    int idx = blockIdx.x * 256 + threadIdx.x;   // 10240 dwords
    if (idx >= 10240) return;
    int j2 = idx & 3, l = (idx >> 2) & 63, r = idx >> 8;
    int split = r & 1, s = (r >> 1) & 1, n = r >> 2;
    int col = 16 * n + (l & 15);
    unsigned bits[2];
    #pragma unroll
    for (int q = 0; q < 2; ++q) {
        int k = 32 * s + 8 * (l >> 4) + 2 * j2 + q;
        float v = (col < 152) ? ws[WS_W4T + k * 152 + col] : 0.f;
        unsigned hb = rnbf16_bits(v);
        if (split == 0) bits[q] = hb;
        else {
            float fh = __uint_as_float(hb << 16);
            bits[q] = rnbf16_bits(v - fh);
        }
    }
    reinterpret_cast<unsigned*>(ws)[WS_W4F + idx] = bits[0] | (bits[1] << 16);
}

// ---------------------------------------------------------------------------
// precompute kernel 4: pack WHH / W3V / W3QK into B-fragment order.
// ---------------------------------------------------------------------------
__global__ void k_pre4(float* ws)
{
    int idx = blockIdx.x * 256 + threadIdx.x;
    if (idx >= 77824) return;
    const float* src; int N, rel, dst;
    if (idx < 16384)      { src = ws + WS_WHHT; N = 256; rel = idx;         dst = WS_GF + idx; }
    else if (idx < 36864) { src = ws + WS_W3V;  N = 320; rel = idx - 16384; dst = WS_VF + rel; }
    else {
        int r = idx - 36864;
        int h = r / 10240;  rel = r % 10240;
        src = ws + WS_W3QK + h * 10240; N = 160;
        dst = WS_QKF + r;
    }
    int n = rel >> 10, sub = rel & 1023;
    int s = sub >> 9, split = (sub >> 8) & 1, lj = sub & 255;
    int l = lj >> 2, j2 = lj & 3;
    int col = n * 16 + (l & 15);
    unsigned bits[2];
    #pragma unroll
    for (int q = 0; q < 2; ++q) {
        int k = 32 * s + 8 * (l >> 4) + 2 * j2 + q;
        float v = src[k * N + col];
        unsigned hb = rnbf16_bits(v);
        if (split == 0) bits[q] = hb;
        else bits[q] = rnbf16_bits(v - __uint_as_float(hb << 16));
    }
    reinterpret_cast<unsigned*>(ws)[dst] = bits[0] | (bits[1] << 16);
}

// ---------------------------------------------------------------------------
// helpers
// ---------------------------------------------------------------------------
__device__ __forceinline__ float sigf(float v) {
    return __builtin_amdgcn_rcpf(1.f + __expf(-v));
}
__device__ __forceinline__ float tanh_fast(float v) {
    float e = __expf(-2.f * v);
    return fmaf(-2.f, e * __builtin_amdgcn_rcpf(1.f + e), 1.f);   // (1-e)/(1+e)
}

// fp32 kloop (preamble only)
template<int NC, int K, int WS>
__device__ __forceinline__ void kloop(const float* __restrict__ wT,
                                      const float* __restrict__ a_row,
                                      float* acc)
{
    #pragma unroll 4
    for (int k = 0; k < K; k += 4) {
        const float4 av = *reinterpret_cast<const float4*>(a_row + k);
        const float* wr = wT + k * WS;
        #pragma unroll
        for (int c = 0; c < NC; ++c) acc[c] = fmaf(av.x, wr[c], acc[c]);
        #pragma unroll
        for (int c = 0; c < NC; ++c) acc[c] = fmaf(av.y, wr[WS + c], acc[c]);
        #pragma unroll
        for (int c = 0; c < NC; ++c) acc[c] = fmaf(av.z, wr[2 * WS + c], acc[c]);
        #pragma unroll
        for (int c = 0; c < NC; ++c) acc[c] = fmaf(av.w, wr[3 * WS + c], acc[c]);
    }
}

// one 16x16 output tile, K=64, bf16x3: 6 MFMA. base = frag ptr for this n-tile.
__device__ __forceinline__ f32x4 mfma_tile(const bf16x8* __restrict__ base,
                                           const bf16x8* ah, const bf16x8* al,
                                           int l, f32x4 acc)
{
    #pragma unroll
    for (int s = 0; s < 2; ++s) {
        bf16x8 bh = base[s * 128 + l];
        bf16x8 bl = base[s * 128 + 64 + l];
        acc = __builtin_amdgcn_mfma_f32_16x16x32_bf16(al[s], bh, acc, 0, 0, 0);
        acc = __builtin_amdgcn_mfma_f32_16x16x32_bf16(ah[s], bl, acc, 0, 0, 0);
        acc = __builtin_amdgcn_mfma_f32_16x16x32_bf16(ah[s], bh, acc, 0, 0, 0);
    }
    return acc;
}

// build bf16 hi/lo A-fragments for m-tile m (m in 0..1) from LDS h rows
__device__ __forceinline__ void build_afrag(const float* __restrict__ hbase,
                                            int m, int l, bf16x8* ah, bf16x8* al)
{
    const int arow = m * 16 + (l & 15);
    const int kb   = 8 * (l >> 4);
    #pragma unroll
    for (int s = 0; s < 2; ++s) {
        const float* ap = hbase + arow * HSTR + 32 * s + kb;
        float4 f0 = *reinterpret_cast<const float4*>(ap);
        float4 f1 = *reinterpret_cast<const float4*>(ap + 4);
        float fv[8] = {f0.x, f0.y, f0.z, f0.w, f1.x, f1.y, f1.z, f1.w};
        #pragma unroll
        for (int j = 0; j < 8; ++j) {
            unsigned hb = rnbf16_bits(fv[j]);
            ah[s][j] = (short)hb;
            al[s][j] = (short)rnbf16_bits(fv[j] - __uint_as_float(hb << 16));
        }
    }
}

// ---------------------------------------------------------------------------
// main fused kernel: 1 block = 32 batch elements, 512 threads = 8 waves
// ---------------------------------------------------------------------------
__global__ void __launch_bounds__(512, 2)
policy_main(const float* __restrict__ x,
            const float* __restrict__ fc1_b, const float* __restrict__ fc2_b,
            const float* __restrict__ h0_b,  const float* __restrict__ c0_b,
            const float* __restrict__ ws,    float* __restrict__ out)
{
    __shared__ float lds[LDS_DW];

    const int tid = threadIdx.x;
    const int l   = tid & 63;
    const int w   = RF(tid >> 6);            // 0..7
    const int m   = w & 1;                   // m-tile (16 rows) of this wave
    const int g   = w >> 1;                  // n-group 0..3
    const int el  = l & 31;                  // element within tile
    const int hf  = l >> 5;                  // col-half for preamble
    const int e0  = blockIdx.x * 32;
    const int r0c = (l >> 4) << 2;           // C-fragment row base
    const int cl16 = l & 15;
    const int kb   = 8 * (l >> 4);

    // ---- stage x tile (zero-pad cols 150..155) ----
    for (int idx = tid; idx < 32 * XSTR; idx += 512) {
        int r = idx / XSTR, k = idx - r * XSTR;
        lds[idx] = (k < 150) ? x[(e0 + r) * 150 + k] : 0.f;
    }
    __syncthreads();

    // ---- fc1 -> h1 (relu) : 8 waves x (2 halves x 4 cols) ----
    {
        const int c0 = w * 8 + hf * 4;
        float acc[4];
        #pragma unroll
        for (int c = 0; c < 4; ++c) acc[c] = fc1_b[c0 + c];
        kloop<4, 152, 64>(ws + WS_FC1T + c0, lds + el * XSTR, acc);
        float* hp = lds + H1_OFF + el * HSTR + c0;
        *reinterpret_cast<float4*>(hp) =
            make_float4(fmaxf(acc[0],0.f), fmaxf(acc[1],0.f), fmaxf(acc[2],0.f), fmaxf(acc[3],0.f));
    }
    __syncthreads();

    // ---- fc2 -> h2 (relu) ----
    {
        const int c0 = w * 8 + hf * 4;
        float acc[4];
        #pragma unroll
        for (int c = 0; c < 4; ++c) acc[c] = fc2_b[c0 + c];
        kloop<4, 64, 64>(ws + WS_FC2T + c0, lds + H1_OFF + el * HSTR, acc);
        float* hp = lds + H2_OFF + el * HSTR + c0;
        *reinterpret_cast<float4*>(hp) =
            make_float4(fmaxf(acc[0],0.f), fmaxf(acc[1],0.f), fmaxf(acc[2],0.f), fmaxf(acc[3],0.f));
    }
    __syncthreads();

    // ---- fc3 + action softmax (wave 0, lanes<32) | h0,c0 (waves 1..7) ----
    if (w == 0) {
        if (hf == 0) {
            float acc[12];
            #pragma unroll
            for (int c = 0; c < 12; ++c) acc[c] = ws[WS_FC3B + c];
            kloop<12, 64, 12>(ws + WS_FC3T, lds + H2_OFF + el * HSTR, acc);
            float mm = acc[0];
            #pragma unroll
            for (int i = 1; i < 10; ++i) mm = fmaxf(mm, acc[i]);
            float sum = 0.f;
            #pragma unroll
            for (int i = 0; i < 10; ++i) { acc[i] = __expf(acc[i] - mm); sum += acc[i]; }
            float inv = __builtin_amdgcn_rcpf(sum);
            float* op = out + (size_t)(e0 + el) * 10;
            #pragma unroll
            for (int i = 0; i < 10; i += 2)
                *reinterpret_cast<float2*>(op + i) = make_float2(acc[i] * inv, acc[i + 1] * inv);
        }
    } else {
        for (int j = w - 1; j < 16; j += 7) {
            const int  cc  = (j & 7) * 8 + hf * 4;
            const bool isC = (j >= 8);
            const float* wT = ws + (isC ? WS_C0T : WS_H0T) + cc;
            const float* bb = isC ? c0_b : h0_b;
            float acc[4];
            #pragma unroll
            for (int c = 0; c < 4; ++c) acc[c] = bb[cc + c];
            kloop<4, 64, 64>(wT, lds + H2_OFF + el * HSTR, acc);
            float* dp = lds + (isC ? C_OFF : H_OFF) + el * HSTR + cc;
            *reinterpret_cast<float4*>(dp) = make_float4(acc[0], acc[1], acc[2], acc[3]);
        }
    }
    __syncthreads();

    const bf16x8* gfrag  = reinterpret_cast<const bf16x8*>(ws + WS_GF);
    const bf16x8* vfrag  = reinterpret_cast<const bf16x8*>(ws + WS_VF);
    const bf16x8* qkfrag = reinterpret_cast<const bf16x8*>(ws + WS_QKF);
    const bf16x8* wb     = reinterpret_cast<const bf16x8*>(ws + WS_W4F);

    // score-phase thread mapping: tid<320, grp 0..9, team 0..4, half 0..1
    const int grp  = tid >> 5;
    const int sel  = tid & 31;
    const int team = (grp < 5) ? grp : grp - 5;
    const int half = (grp < 5) ? 0 : 1;
    const int jcol = g * 16 + cl16;          // gate column owned in fused S1

    // S7 half-job executor for step sst: jobs {w, w+8, w+16<20}
    auto do_s7 = [&](int sst) {
        #pragma unroll 1
        for (int job = w; job < 20; job += 8) {
            const int t  = job >> 2;         // 0..4
            const int mj = (job >> 1) & 1;   // 0..1
            const int nh = job & 1;          // n-half 0..1
            const int arow = mj * 16 + cl16;
            bf16x8 ah2[2], al2[2];
            #pragma unroll
            for (int s = 0; s < 2; ++s) {
                const float* ap = lds + arow * VSTR + t * 64 + 32 * s + kb;
                float4 f0 = *reinterpret_cast<const float4*>(ap);
                float4 f1 = *reinterpret_cast<const float4*>(ap + 4);
                float fv[8] = {f0.x, f0.y, f0.z, f0.w, f1.x, f1.y, f1.z, f1.w};
                #pragma unroll
                for (int j = 0; j < 8; ++j) {
                    unsigned hb = rnbf16_bits(fv[j]);
                    float fh = __uint_as_float(hb << 16);
                    ah2[s][j] = (short)hb;
                    al2[s][j] = (short)rnbf16_bits(fv[j] - fh);
                }
            }
            #pragma unroll 1
            for (int i = 0; i < 5; ++i) {
                const int n = nh * 5 + i;
                const int c = n * 16 + cl16;
                float bias = ws[WS_B4 + (c < 151 ? c : 151)];
                f32x4 acc = {bias, bias, bias, bias};
                acc = mfma_tile(wb + n * 256, ah2, al2, l, acc);
                if (c < 150) {
                    const int r0 = mj * 16 + r0c;
                    #pragma unroll
                    for (int q = 0; q < 4; ++q)
                        out[(size_t)BATCH * 10 +
                            ((size_t)((e0 + r0 + q) * 5 + sst) * 5 + t) * 150 + c] = acc[q];
                }
            }
        }
    };

    // ================== LSTM / attention steps ==================
    #pragma unroll 1
    for (int st = 0; st < 5; ++st) {
        // ---- Phase A: S7(st-1) + S1 gates MFMA -> gacc regs ----
        f32x4 gacc[4];
        {
            if (st > 0) do_s7(st - 1);       // reads VBUF att; disjoint from H/C
            bf16x8 ah[2], al[2];
            build_afrag(lds + H_OFF, m, l, ah, al);   // reads h_old
            #pragma unroll 1
            for (int gi = 0; gi < 4; ++gi) {
                const int n = gi * 4 + g;            // tile for gate gi, col jcol
                float b = ws[WS_GB + gi * 64 + jcol];
                f32x4 acc = {b, b, b, b};
                gacc[gi] = mfma_tile(gfrag + n * 256, ah, al, l, acc);
            }
        }
        __syncthreads();     // all h_old reads complete before h_new writes

        // ---- Phase B: in-register LSTM pointwise, write h/c ----
        {
            #pragma unroll
            for (int q = 0; q < 4; ++q) {
                const int row = m * 16 + r0c + q;
                float c_ = lds[C_OFF + row * HSTR + jcol];
                float cc = sigf(gacc[1][q]) * c_ + sigf(gacc[0][q]) * tanh_fast(gacc[2][q]);
                float hn = sigf(gacc[3][q]) * tanh_fast(cc);
                lds[C_OFF + row * HSTR + jcol] = cc;
                lds[H_OFF + row * HSTR + jcol] = hn;
            }
        }
        __syncthreads();

        // ---- Phase C: v (5 tiles) + qk head0; A-frags persist to qk3 ----
        bf16x8 ah[2], al[2];
        build_afrag(lds + H_OFF, m, l, ah, al);
        {
            #pragma unroll 1
            for (int i = 0; i < 5; ++i) {
                const int n   = g * 5 + i;
                const int col = n * 16 + cl16;
                float b = ws[WS_B3V + col];
                f32x4 acc = {b, b, b, b};
                acc = mfma_tile(vfrag + n * 256, ah, al, l, acc);
                #pragma unroll
                for (int q = 0; q < 4; ++q)
                    lds[(m * 16 + r0c + q) * VSTR + col] = acc[q];
            }
            #pragma unroll 1
            for (int n = g; n < 10; n += 4) {
                const int col = n * 16 + cl16;
                float b = ws[WS_B3QK + col];
                f32x4 acc = {b, b, b, b};
                acc = mfma_tile(qkfrag + n * 256, ah, al, l, acc);
                #pragma unroll
                for (int q = 0; q < 4; ++q)
                    lds[QK_OFF + (m * 16 + r0c + q) * QKSTR + col] = acc[q];
            }
        }
        __syncthreads();

        // ---- per-head: scores+softmax+PV(half) | att-write + next qk ----
        float att[8];
        #pragma unroll 1
        for (int h = 0; h < 4; ++h) {
            if (tid < 320) {
                const float* qk = lds + QK_OFF + sel * QKSTR;
                float4 q0 = *reinterpret_cast<const float4*>(qk + team * 32);
                float4 q1 = *reinterpret_cast<const float4*>(qk + team * 32 + 4);
                float4 q2 = *reinterpret_cast<const float4*>(qk + team * 32 + 8);
                float4 q3 = *reinterpret_cast<const float4*>(qk + team * 32 + 12);
                float sc[5];
                #pragma unroll 2
                for (int t2 = 0; t2 < 5; ++t2) {
                    const float* kp = qk + t2 * 32 + 16;
                    float4 k0 = *reinterpret_cast<const float4*>(kp);
                    float4 k1 = *reinterpret_cast<const float4*>(kp + 4);
                    float4 k2 = *reinterpret_cast<const float4*>(kp + 8);
                    float4 k3 = *reinterpret_cast<const float4*>(kp + 12);
                    float d0 = q0.x * k0.x; d0 = fmaf(q0.y, k0.y, d0); d0 = fmaf(q0.z, k0.z, d0); d0 = fmaf(q0.w, k0.w, d0);
                    float d1 = q1.x * k1.x; d1 = fmaf(q1.y, k1.y, d1); d1 = fmaf(q1.z, k1.z, d1); d1 = fmaf(q1.w, k1.w, d1);
                    float d2 = q2.x * k2.x; d2 = fmaf(q2.y, k2.y, d2); d2 = fmaf(q2.z, k2.z, d2); d2 = fmaf(q2.w, k2.w, d2);
                    float d3 = q3.x * k3.x; d3 = fmaf(q3.y, k3.y, d3); d3 = fmaf(q3.z, k3.z, d3); d3 = fmaf(q3.w, k3.w, d3);
                    sc[t2] = (d0 + d1) + (d2 + d3);
                }
                float mm = fmaxf(fmaxf(fmaxf(sc[0], sc[1]), fmaxf(sc[2], sc[3])), sc[4]);
                float p[5];
                float sum = 0.f;
                #pragma unroll
                for (int t2 = 0; t2 < 5; ++t2) { p[t2] = __expf(sc[t2] - mm); sum += p[t2]; }
                float inv = __builtin_amdgcn_rcpf(sum);
                #pragma unroll
                for (int t2 = 0; t2 < 5; ++t2) p[t2] *= inv;

                #pragma unroll
                for (int r = 0; r < 8; ++r) att[r] = 0.f;
                const float* vr = lds + sel * VSTR + h * 16 + half * 8;
                #pragma unroll 2
                for (int t2 = 0; t2 < 5; ++t2) {
                    float4 v0 = *reinterpret_cast<const float4*>(vr + t2 * 64);
                    float4 v1 = *reinterpret_cast<const float4*>(vr + t2 * 64 + 4);
                    att[0] = fmaf(p[t2], v0.x, att[0]);
                    att[1] = fmaf(p[t2], v0.y, att[1]);
                    att[2] = fmaf(p[t2], v0.z, att[2]);
                    att[3] = fmaf(p[t2], v0.w, att[3]);
                    att[4] = fmaf(p[t2], v1.x, att[4]);
                    att[5] = fmaf(p[t2], v1.y, att[5]);
                    att[6] = fmaf(p[t2], v1.z, att[6]);
                    att[7] = fmaf(p[t2], v1.w, att[7]);
                }
            }
            __syncthreads();   // v reads done; att safe to overwrite v slots

            if (tid < 320) {
                float* ap = lds + sel * VSTR + team * 64 + h * 16 + half * 8;
                *reinterpret_cast<float4*>(ap)     = make_float4(att[0], att[1], att[2], att[3]);
                *reinterpret_cast<float4*>(ap + 4) = make_float4(att[4], att[5], att[6], att[7]);
            }
            if (h < 3) {       // qk (MFMA) for head h+1, persistent A-frags
                #pragma unroll 1
                for (int n = g; n < 10; n += 4) {
                    const int col = n * 16 + cl16;
                    float b = ws[WS_B3QK + (h + 1) * 160 + col];
                    f32x4 acc = {b, b, b, b};
                    acc = mfma_tile(qkfrag + (h + 1) * 2560 + n * 256, ah, al, l, acc);
                    #pragma unroll
                    for (int q = 0; q < 4; ++q)
                        lds[QK_OFF + (m * 16 + r0c + q) * QKSTR + col] = acc[q];
                }
            }
            __syncthreads();
        }
    }

    // ---- final S7 for the last step (att still live in VBUF) ----
    do_s7(4);
}

// ---------------------------------------------------------------------------
extern "C" void kernel_launch(void* const* d_in, const int* in_sizes, int n_in,
                              void* d_out, int out_size, void* d_ws, size_t ws_size,
                              hipStream_t stream)
{
    const float* x        = (const float*)d_in[0];
    const float* fc1_w    = (const float*)d_in[1];
    const float* fc1_b    = (const float*)d_in[2];
    const float* fc2_w    = (const float*)d_in[3];
    const float* fc2_b    = (const float*)d_in[4];
    const float* fc3_w    = (const float*)d_in[5];
    const float* fc3_b    = (const float*)d_in[6];
    const float* h0_w     = (const float*)d_in[7];
    const float* h0_b     = (const float*)d_in[8];
    const float* c0_w     = (const float*)d_in[9];
    const float* c0_b     = (const float*)d_in[10];
    // d_in[11] = lstm_wih : unused (LSTM input is all-zeros)
    const float* lstm_whh = (const float*)d_in[12];
    const float* lstm_bih = (const float*)d_in[13];
    const float* lstm_bhh = (const float*)d_in[14];
    const float* predfc_w = (const float*)d_in[15];
    const float* predfc_b = (const float*)d_in[16];
    const float* emb_w    = (const float*)d_in[17];
    const float* emb_b    = (const float*)d_in[18];
    const float* attn_in_w= (const float*)d_in[19];
    const float* attn_in_b= (const float*)d_in[20];
    const float* attn_out_w=(const float*)d_in[21];
    const float* attn_out_b=(const float*)d_in[22];
    const float* unemb_w  = (const float*)d_in[23];
    const float* unemb_b  = (const float*)d_in[24];

    float* ws  = (float*)d_ws;
    float* outp= (float*)d_out;

    k_pre1<<<(PRE1_ITEMS + 255) / 256, 256, 0, stream>>>(
        fc1_w, fc2_w, fc3_w, fc3_b, h0_w, c0_w,
        lstm_whh, lstm_bih, lstm_bhh,
        predfc_w, predfc_b, emb_w, emb_b,
        attn_out_w, attn_out_b, unemb_w, unemb_b, ws);

    k_pre2<<<(PRE2_ITEMS + 255) / 256, 256, 0, stream>>>(attn_in_w, attn_in_b, ws);

    k_pre3<<<40, 256, 0, stream>>>(ws);
    k_pre4<<<304, 256, 0, stream>>>(ws);

    policy_main<<<BATCH / 32, 512, 0, stream>>>(
        x, fc1_b, fc2_b, h0_b, c0_b, ws, outp);
}

// Round 18
// 231.347 us; speedup vs baseline: 1.4306x; 1.4306x over previous
//
#include <hip/hip_runtime.h>

// ---------------------------------------------------------------------------
// PolicyNet fused forward, MFMA bf16x3 step loop, MI355X.
// Round 18: revert R17 (gacc-across-barrier -> occupancy halved). R15
// structure (race-free, unroll-1, arch 52, spill-free) ported to 16-elem /
// 256-thread / 4-wave blocks at (256,2): same 16 waves/CU but as FOUR
// independent barrier domains (LDS 4x39936=159744<=160KB), so barrier
// drains of one block overlap compute of three others (R15 had only 2).
// R13 proved geometry; R15's unroll-1 codegen provides the <=64-reg alloc.
// Numerics identical to R4..R17 (absmax 4.88e-4).
// ---------------------------------------------------------------------------

#define RF(x) __builtin_amdgcn_readfirstlane(x)

constexpr int BATCH = 16384;

typedef short bf16x8 __attribute__((ext_vector_type(8)));
typedef float f32x4  __attribute__((ext_vector_type(4)));

// ---- workspace layout (dwords) ----
constexpr int WS_FC1T = 0;       // [152][64]  fc1_w^T (zero-padded K)
constexpr int WS_FC2T = 9728;    // [64][64]
constexpr int WS_FC3T = 13824;   // [64][12]   (cols 10,11 zero)
constexpr int WS_H0T  = 14592;   // [64][64]
constexpr int WS_C0T  = 18688;   // [64][64]
constexpr int WS_WHHT = 22784;   // [64][256]  whh^T, col = gate*64+j (i,f,g,o)
constexpr int WS_GB   = 39168;   // [256]      bih+bhh
constexpr int WS_W2   = 39424;   // [5][64][64]   emb_w @ predfc_w_t
constexpr int WS_B2   = 59904;   // [5][64]
constexpr int WS_W3QK = 60224;   // [4][64][160]  per head: [k][t*32 + (q0..15|k16..31)]
constexpr int WS_W3V  = 101184;  // [64][320]     [k][t*64 + h*16 + d]
constexpr int WS_B3QK = 121664;  // [4][160]
constexpr int WS_B3V  = 122304;  // [320]
constexpr int WS_W4T  = 122624;  // [64][152]  (unemb_w @ attn_out_w)^T
constexpr int WS_B4   = 132352;  // [152]
constexpr int WS_FC3B = 132504;  // [12]
constexpr int WS_W4F  = 132520;  // [10n][2s][2split][64l][4dw] bf16 B-frags (S7)
constexpr int WS_GF   = 142760;  // gates frags: 16 n-tiles  (16384 dw)
constexpr int WS_VF   = 159144;  // v frags:     20 n-tiles  (20480 dw)
constexpr int WS_QKF  = 179624;  // qk frags: 4 heads x 10 n (40960 dw)
constexpr int WS_TOTAL= 220584;  // dwords (~882 KB)

// ---- LDS layout (dwords), 16-row tile ----
constexpr int VSTR     = 324;    // VBUF [16][324]: gates / v / att (x, h2 alias)
constexpr int QK_OFF   = 5184;   // [16][164]  (h1 aliases)
constexpr int QKSTR    = 164;
constexpr int H_OFF    = 7808;   // [16][68]
constexpr int C_OFF    = 8896;   // [16][68]
constexpr int HSTR     = 68;
constexpr int XSTR     = 156;    // x staged at VBUF offset 0
constexpr int H1_OFF   = QK_OFF;
constexpr int H2_OFF   = 2496;   // after x within VBUF
constexpr int LDS_DW   = 9984;   // 39936 bytes -> 4 blocks/CU at <=128 total regs

// ---------------------------------------------------------------------------
__device__ __forceinline__ unsigned rnbf16_bits(float f) {
    unsigned u = __float_as_uint(f);
    return (u + 0x7FFFu + ((u >> 16) & 1u)) >> 16;   // round-nearest-even
}

// ---------------------------------------------------------------------------
// precompute kernel 1: transposes + W2/b2 + W4/b4 + misc biases
// ---------------------------------------------------------------------------
__global__ void k_pre1(const float* __restrict__ fc1_w, const float* __restrict__ fc2_w,
                       const float* __restrict__ fc3_w, const float* __restrict__ fc3_b,
                       const float* __restrict__ h0_w,  const float* __restrict__ c0_w,
                       const float* __restrict__ whh,   const float* __restrict__ bih,
                       const float* __restrict__ bhh,
                       const float* __restrict__ predfc_w, const float* __restrict__ predfc_b,
                       const float* __restrict__ emb_w,    const float* __restrict__ emb_b,
                       const float* __restrict__ aow, const float* __restrict__ aob,
                       const float* __restrict__ unw, const float* __restrict__ unb,
                       float* ws)
{
    int idx = blockIdx.x * 256 + threadIdx.x;
    if (idx < 9728) { int k = idx / 64, c = idx & 63;
        ws[WS_FC1T + idx] = (k < 150) ? fc1_w[c * 150 + k] : 0.f; return; }
    idx -= 9728;
    if (idx < 4096) { int k = idx >> 6, c = idx & 63; ws[WS_FC2T + idx] = fc2_w[c * 64 + k]; return; }
    idx -= 4096;
    if (idx < 768)  { int k = idx / 12, c = idx % 12;
        ws[WS_FC3T + idx] = (c < 10) ? fc3_w[c * 64 + k] : 0.f; return; }
    idx -= 768;
    if (idx < 4096) { int k = idx >> 6, c = idx & 63; ws[WS_H0T + idx] = h0_w[c * 64 + k]; return; }
    idx -= 4096;
    if (idx < 4096) { int k = idx >> 6, c = idx & 63; ws[WS_C0T + idx] = c0_w[c * 64 + k]; return; }
    idx -= 4096;
    if (idx < 16384){ int k = idx >> 8, c = idx & 255; ws[WS_WHHT + idx] = whh[c * 64 + k]; return; }
    idx -= 16384;
    if (idx < 256)  { ws[WS_GB + idx] = bih[idx] + bhh[idx]; return; }
    idx -= 256;
    if (idx < 20480){ int t = idx / 4096, r = idx & 4095, kk = r >> 6, j = r & 63;
        float s = 0.f;
        for (int m = 0; m < 150; ++m)
            s = fmaf(emb_w[kk * 150 + m], predfc_w[(t * 150 + m) * 64 + j], s);
        ws[WS_W2 + idx] = s; return; }
    idx -= 20480;
    if (idx < 320)  { int t = idx / 64, kk = idx & 63;
        float s = emb_b[kk];
        for (int m = 0; m < 150; ++m)
            s = fmaf(emb_w[kk * 150 + m], predfc_b[t * 150 + m], s);
        ws[WS_B2 + idx] = s; return; }
    idx -= 320;
    if (idx < 9728) { int k = idx / 152, ss = idx % 152;
        float v = 0.f;
        if (ss < 150) { float a = 0.f;
            for (int kk = 0; kk < 64; ++kk) a = fmaf(unw[ss * 64 + kk], aow[kk * 64 + k], a);
            v = a; }
        ws[WS_W4T + idx] = v; return; }
    idx -= 9728;
    if (idx < 152)  { float v = 0.f;
        if (idx < 150) { float a = unb[idx];
            for (int kk = 0; kk < 64; ++kk) a = fmaf(unw[idx * 64 + kk], aob[kk], a);
            v = a; }
        ws[WS_B4 + idx] = v; return; }
    idx -= 152;
    if (idx < 12)   { ws[WS_FC3B + idx] = (idx < 10) ? fc3_b[idx] : 0.f; return; }
}
constexpr int PRE1_ITEMS = 70116;

// ---------------------------------------------------------------------------
// precompute kernel 2: W3 = attn_in_w @ W2  (q rows scaled by 0.25), b3
// ---------------------------------------------------------------------------
__global__ void k_pre2(const float* __restrict__ aiw, const float* __restrict__ aib,
                       float* ws)
{
    int idx = blockIdx.x * 256 + threadIdx.x;
    const float* W2 = ws + WS_W2;
    const float* b2 = ws + WS_B2;
    if (idx < 40960) {
        int h = idx / 10240, r = idx % 10240, k = r / 160, c = r % 160;
        int t = c / 32, rr = c % 32;
        int row; float scale;
        if (rr < 16) { row = h * 16 + rr;            scale = 0.25f; }
        else         { row = 64 + h * 16 + (rr - 16); scale = 1.f;  }
        float s = 0.f;
        for (int kk = 0; kk < 64; ++kk)
            s = fmaf(aiw[row * 64 + kk], W2[t * 4096 + kk * 64 + k], s);
        ws[WS_W3QK + idx] = s * scale; return;
    }
    idx -= 40960;
    if (idx < 20480) {
        int k = idx / 320, c = idx % 320, t = c >> 6, r3 = c & 63;
        int row = 128 + r3;
        float s = 0.f;
        for (int kk = 0; kk < 64; ++kk)
            s = fmaf(aiw[row * 64 + kk], W2[t * 4096 + kk * 64 + k], s);
        ws[WS_W3V + idx] = s; return;
    }
    idx -= 20480;
    if (idx < 640) {
        int h = idx / 160, c = idx % 160, t = c / 32, rr = c % 32;
        int row; float scale;
        if (rr < 16) { row = h * 16 + rr;            scale = 0.25f; }
        else         { row = 64 + h * 16 + (rr - 16); scale = 1.f;  }
        float s = aib[row];
        for (int kk = 0; kk < 64; ++kk)
            s = fmaf(aiw[row * 64 + kk], b2[t * 64 + kk], s);
        ws[WS_B3QK + idx] = s * scale; return;
    }
    idx -= 640;
    if (idx < 320) {
        int t = idx >> 6, r3 = idx & 63, row = 128 + r3;
        float s = aib[row];
        for (int kk = 0; kk < 64; ++kk)
            s = fmaf(aiw[row * 64 + kk], b2[t * 64 + kk], s);
        ws[WS_B3V + idx] = s; return;
    }
}
constexpr int PRE2_ITEMS = 62400;

// ---------------------------------------------------------------------------
// precompute kernel 3: W4 bf16 hi/lo B-fragment pack (validated R4).
// ---------------------------------------------------------------------------
__global__ void k_pre3(float* ws)
{
    int idx = blockIdx.x * 256 + threadIdx.x;   // 10240 dwords
    if (idx >= 10240) return;
    int j2 = idx & 3, l = (idx >> 2) & 63, r = idx >> 8;
    int split = r & 1, s = (r >> 1) & 1, n = r >> 2;
    int col = 16 * n + (l & 15);
    unsigned bits[2];
    #pragma unroll
    for (int q = 0; q < 2; ++q) {
        int k = 32 * s + 8 * (l >> 4) + 2 * j2 + q;
        float v = (col < 152) ? ws[WS_W4T + k * 152 + col] : 0.f;
        unsigned hb = rnbf16_bits(v);
        if (split == 0) bits[q] = hb;
        else {
            float fh = __uint_as_float(hb << 16);
            bits[q] = rnbf16_bits(v - fh);
        }
    }
    reinterpret_cast<unsigned*>(ws)[WS_W4F + idx] = bits[0] | (bits[1] << 16);
}

// ---------------------------------------------------------------------------
// precompute kernel 4: pack WHH / W3V / W3QK into B-fragment order.
// ---------------------------------------------------------------------------
__global__ void k_pre4(float* ws)
{
    int idx = blockIdx.x * 256 + threadIdx.x;
    if (idx >= 77824) return;
    const float* src; int N, rel, dst;
    if (idx < 16384)      { src = ws + WS_WHHT; N = 256; rel = idx;         dst = WS_GF + idx; }
    else if (idx < 36864) { src = ws + WS_W3V;  N = 320; rel = idx - 16384; dst = WS_VF + rel; }
    else {
        int r = idx - 36864;
        int h = r / 10240;  rel = r % 10240;
        src = ws + WS_W3QK + h * 10240; N = 160;
        dst = WS_QKF + r;
    }
    int n = rel >> 10, sub = rel & 1023;
    int s = sub >> 9, split = (sub >> 8) & 1, lj = sub & 255;
    int l = lj >> 2, j2 = lj & 3;
    int col = n * 16 + (l & 15);
    unsigned bits[2];
    #pragma unroll
    for (int q = 0; q < 2; ++q) {
        int k = 32 * s + 8 * (l >> 4) + 2 * j2 + q;
        float v = src[k * N + col];
        unsigned hb = rnbf16_bits(v);
        if (split == 0) bits[q] = hb;
        else bits[q] = rnbf16_bits(v - __uint_as_float(hb << 16));
    }
    reinterpret_cast<unsigned*>(ws)[dst] = bits[0] | (bits[1] << 16);
}

// ---------------------------------------------------------------------------
// helpers
// ---------------------------------------------------------------------------
__device__ __forceinline__ float sigf(float v) {
    return __builtin_amdgcn_rcpf(1.f + __expf(-v));
}
__device__ __forceinline__ float tanh_fast(float v) {
    float e = __expf(-2.f * v);
    return fmaf(-2.f, e * __builtin_amdgcn_rcpf(1.f + e), 1.f);   // (1-e)/(1+e)
}

// fp32 kloop (preamble only)
template<int NC, int K, int WS>
__device__ __forceinline__ void kloop(const float* __restrict__ wT,
                                      const float* __restrict__ a_row,
                                      float* acc)
{
    #pragma unroll 4
    for (int k = 0; k < K; k += 4) {
        const float4 av = *reinterpret_cast<const float4*>(a_row + k);
        const float* wr = wT + k * WS;
        #pragma unroll
        for (int c = 0; c < NC; ++c) acc[c] = fmaf(av.x, wr[c], acc[c]);
        #pragma unroll
        for (int c = 0; c < NC; ++c) acc[c] = fmaf(av.y, wr[WS + c], acc[c]);
        #pragma unroll
        for (int c = 0; c < NC; ++c) acc[c] = fmaf(av.z, wr[2 * WS + c], acc[c]);
        #pragma unroll
        for (int c = 0; c < NC; ++c) acc[c] = fmaf(av.w, wr[3 * WS + c], acc[c]);
    }
}

// one 16x16 output tile, K=64, bf16x3: 6 MFMA. base = frag ptr for this n-tile.
__device__ __forceinline__ f32x4 mfma_tile(const bf16x8* __restrict__ base,
                                           const bf16x8* ah, const bf16x8* al,
                                           int l, f32x4 acc)
{
    #pragma unroll
    for (int s = 0; s < 2; ++s) {
        bf16x8 bh = base[s * 128 + l];
        bf16x8 bl = base[s * 128 + 64 + l];
        acc = __builtin_amdgcn_mfma_f32_16x16x32_bf16(al[s], bh, acc, 0, 0, 0);
        acc = __builtin_amdgcn_mfma_f32_16x16x32_bf16(ah[s], bl, acc, 0, 0, 0);
        acc = __builtin_amdgcn_mfma_f32_16x16x32_bf16(ah[s], bh, acc, 0, 0, 0);
    }
    return acc;
}

// build bf16 hi/lo A-fragments (single 16-row m-tile) from LDS rows
__device__ __forceinline__ void build_afrag(const float* __restrict__ hbase,
                                            int l, bf16x8* ah, bf16x8* al)
{
    const int arow = l & 15;
    const int kb   = 8 * (l >> 4);
    #pragma unroll
    for (int s = 0; s < 2; ++s) {
        const float* ap = hbase + arow * HSTR + 32 * s + kb;
        float4 f0 = *reinterpret_cast<const float4*>(ap);
        float4 f1 = *reinterpret_cast<const float4*>(ap + 4);
        float fv[8] = {f0.x, f0.y, f0.z, f0.w, f1.x, f1.y, f1.z, f1.w};
        #pragma unroll
        for (int j = 0; j < 8; ++j) {
            unsigned hb = rnbf16_bits(fv[j]);
            ah[s][j] = (short)hb;
            al[s][j] = (short)rnbf16_bits(fv[j] - __uint_as_float(hb << 16));
        }
    }
}

// ---------------------------------------------------------------------------
// main fused kernel: 1 block = 16 batch elements, 256 threads = 4 waves
// ---------------------------------------------------------------------------
__global__ void __launch_bounds__(256, 2)
policy_main(const float* __restrict__ x,
            const float* __restrict__ fc1_b, const float* __restrict__ fc2_b,
            const float* __restrict__ h0_b,  const float* __restrict__ c0_b,
            const float* __restrict__ ws,    float* __restrict__ out)
{
    __shared__ float lds[LDS_DW];

    const int tid = threadIdx.x;
    const int l   = tid & 63;
    const int w   = RF(tid >> 6);            // 0..3
    const int el  = l & 15;                  // element within tile (preamble)
    const int q4  = l >> 4;                  // quarter 0..3 (preamble cols)
    const int e0  = blockIdx.x * 16;
    const int r0c = (l >> 4) << 2;           // C-fragment row base
    const int cl16 = l & 15;

    // ---- stage x tile (zero-pad cols 150..155) ----
    for (int idx = tid; idx < 16 * XSTR; idx += 256) {
        int r = idx / XSTR, k = idx - r * XSTR;
        lds[idx] = (k < 150) ? x[(e0 + r) * 150 + k] : 0.f;
    }
    __syncthreads();

    // ---- fc1 -> h1 (relu) : 4 waves x 4 quarters x 4 cols ----
    {
        const int c0 = w * 16 + q4 * 4;
        float acc[4];
        #pragma unroll
        for (int c = 0; c < 4; ++c) acc[c] = fc1_b[c0 + c];
        kloop<4, 152, 64>(ws + WS_FC1T + c0, lds + el * XSTR, acc);
        float* hp = lds + H1_OFF + el * HSTR + c0;
        *reinterpret_cast<float4*>(hp) =
            make_float4(fmaxf(acc[0],0.f), fmaxf(acc[1],0.f), fmaxf(acc[2],0.f), fmaxf(acc[3],0.f));
    }
    __syncthreads();

    // ---- fc2 -> h2 (relu) ----
    {
        const int c0 = w * 16 + q4 * 4;
        float acc[4];
        #pragma unroll
        for (int c = 0; c < 4; ++c) acc[c] = fc2_b[c0 + c];
        kloop<4, 64, 64>(ws + WS_FC2T + c0, lds + H1_OFF + el * HSTR, acc);
        float* hp = lds + H2_OFF + el * HSTR + c0;
        *reinterpret_cast<float4*>(hp) =
            make_float4(fmaxf(acc[0],0.f), fmaxf(acc[1],0.f), fmaxf(acc[2],0.f), fmaxf(acc[3],0.f));
    }
    __syncthreads();

    // ---- h0,c0 (16 jobs over 4 waves; each thread 2 cols) + fc3 (wave0) ----
    for (int j = w; j < 16; j += 4) {
        const int  cc  = (j & 7) * 8 + q4 * 2;
        const bool isC = (j >= 8);
        const float* wT = ws + (isC ? WS_C0T : WS_H0T) + cc;
        const float* bb = isC ? c0_b : h0_b;
        float acc[2];
        #pragma unroll
        for (int c = 0; c < 2; ++c) acc[c] = bb[cc + c];
        kloop<2, 64, 64>(wT, lds + H2_OFF + el * HSTR, acc);
        float* dp = lds + (isC ? C_OFF : H_OFF) + el * HSTR + cc;
        *reinterpret_cast<float2*>(dp) = make_float2(acc[0], acc[1]);
    }
    if (w == 0 && q4 == 0) {
        float acc[12];
        #pragma unroll
        for (int c = 0; c < 12; ++c) acc[c] = ws[WS_FC3B + c];
        kloop<12, 64, 12>(ws + WS_FC3T, lds + H2_OFF + el * HSTR, acc);
        float mm = acc[0];
        #pragma unroll
        for (int i = 1; i < 10; ++i) mm = fmaxf(mm, acc[i]);
        float sum = 0.f;
        #pragma unroll
        for (int i = 0; i < 10; ++i) { acc[i] = __expf(acc[i] - mm); sum += acc[i]; }
        float inv = __builtin_amdgcn_rcpf(sum);
        float* op = out + (size_t)(e0 + el) * 10;
        #pragma unroll
        for (int i = 0; i < 10; i += 2)
            *reinterpret_cast<float2*>(op + i) = make_float2(acc[i] * inv, acc[i + 1] * inv);
    }
    __syncthreads();

    const bf16x8* gfrag  = reinterpret_cast<const bf16x8*>(ws + WS_GF);
    const bf16x8* vfrag  = reinterpret_cast<const bf16x8*>(ws + WS_VF);
    const bf16x8* qkfrag = reinterpret_cast<const bf16x8*>(ws + WS_QKF);
    const bf16x8* wb     = reinterpret_cast<const bf16x8*>(ws + WS_W4F);

    // score-phase thread mapping: tid<160, grp 0..9, team 0..4, half 0..1
    const int grp  = tid >> 4;
    const int sel  = tid & 15;
    const int team = (grp < 5) ? grp : grp - 5;
    const int half = (grp < 5) ? 0 : 1;

    // ================== LSTM / attention steps ==================
    #pragma unroll 1
    for (int st = 0; st < 5; ++st) {
        // ---- S1a (MFMA): gates = h @ whh^T + gb : wave -> 4 n-tiles ----
        {
            bf16x8 ah[2], al[2];
            build_afrag(lds + H_OFF, l, ah, al);
            #pragma unroll 1
            for (int i = 0; i < 4; ++i) {
                const int n   = w * 4 + i;
                const int col = n * 16 + cl16;
                float b = ws[WS_GB + col];
                f32x4 acc = {b, b, b, b};
                acc = mfma_tile(gfrag + n * 256, ah, al, l, acc);
                #pragma unroll
                for (int q = 0; q < 4; ++q)
                    lds[(r0c + q) * VSTR + col] = acc[q];
            }
        }
        __syncthreads();

        // ---- S1b: LSTM pointwise (thread: element tid&15, 4 gate cols) ----
        {
            const int ee = tid & 15;
            const int j0 = (tid >> 4) * 4;
            const float* gr = lds + ee * VSTR;
            float* hr = lds + H_OFF + ee * HSTR;
            float* cr = lds + C_OFF + ee * HSTR;
            float4 ig = *reinterpret_cast<const float4*>(gr + j0);
            float4 fg = *reinterpret_cast<const float4*>(gr + 64 + j0);
            float4 gg = *reinterpret_cast<const float4*>(gr + 128 + j0);
            float4 og = *reinterpret_cast<const float4*>(gr + 192 + j0);
            float4 cv = *reinterpret_cast<const float4*>(cr + j0);
            float cn[4], hn[4];
            #pragma unroll
            for (int q = 0; q < 4; ++q) {
                float iv = (&ig.x)[q], fv = (&fg.x)[q], gv = (&gg.x)[q],
                      ov = (&og.x)[q], c_ = (&cv.x)[q];
                float cc = sigf(fv) * c_ + sigf(iv) * tanh_fast(gv);
                cn[q] = cc;
                hn[q] = sigf(ov) * tanh_fast(cc);
            }
            *reinterpret_cast<float4*>(cr + j0) = make_float4(cn[0], cn[1], cn[2], cn[3]);
            *reinterpret_cast<float4*>(hr + j0) = make_float4(hn[0], hn[1], hn[2], hn[3]);
        }
        __syncthreads();

        // ---- S2: v (5 tiles) + qk head0 (phase-local A-frags) ----
        {
            bf16x8 ah[2], al[2];
            build_afrag(lds + H_OFF, l, ah, al);
            #pragma unroll 1
            for (int i = 0; i < 5; ++i) {
                const int n   = w * 5 + i;
                const int col = n * 16 + cl16;
                float b = ws[WS_B3V + col];
                f32x4 acc = {b, b, b, b};
                acc = mfma_tile(vfrag + n * 256, ah, al, l, acc);
                #pragma unroll
                for (int q = 0; q < 4; ++q)
                    lds[(r0c + q) * VSTR + col] = acc[q];
            }
            #pragma unroll 1
            for (int n = w; n < 10; n += 4) {
                const int col = n * 16 + cl16;
                float b = ws[WS_B3QK + col];
                f32x4 acc = {b, b, b, b};
                acc = mfma_tile(qkfrag + n * 256, ah, al, l, acc);
                #pragma unroll
                for (int q = 0; q < 4; ++q)
                    lds[QK_OFF + (r0c + q) * QKSTR + col] = acc[q];
            }
        }
        __syncthreads();

        // ---- per-head: scores+softmax+PV(half) | att-write + next qk ----
        float att[8];
        #pragma unroll 1
        for (int h = 0; h < 4; ++h) {
            if (tid < 160) {
                const float* qk = lds + QK_OFF + sel * QKSTR;
                float4 q0 = *reinterpret_cast<const float4*>(qk + team * 32);
                float4 q1 = *reinterpret_cast<const float4*>(qk + team * 32 + 4);
                float4 q2 = *reinterpret_cast<const float4*>(qk + team * 32 + 8);
                float4 q3 = *reinterpret_cast<const float4*>(qk + team * 32 + 12);
                float sc[5];
                #pragma unroll 2
                for (int t2 = 0; t2 < 5; ++t2) {
                    const float* kp = qk + t2 * 32 + 16;
                    float4 k0 = *reinterpret_cast<const float4*>(kp);
                    float4 k1 = *reinterpret_cast<const float4*>(kp + 4);
                    float4 k2 = *reinterpret_cast<const float4*>(kp + 8);
                    float4 k3 = *reinterpret_cast<const float4*>(kp + 12);
                    float d0 = q0.x * k0.x; d0 = fmaf(q0.y, k0.y, d0); d0 = fmaf(q0.z, k0.z, d0); d0 = fmaf(q0.w, k0.w, d0);
                    float d1 = q1.x * k1.x; d1 = fmaf(q1.y, k1.y, d1); d1 = fmaf(q1.z, k1.z, d1); d1 = fmaf(q1.w, k1.w, d1);
                    float d2 = q2.x * k2.x; d2 = fmaf(q2.y, k2.y, d2); d2 = fmaf(q2.z, k2.z, d2); d2 = fmaf(q2.w, k2.w, d2);
                    float d3 = q3.x * k3.x; d3 = fmaf(q3.y, k3.y, d3); d3 = fmaf(q3.z, k3.z, d3); d3 = fmaf(q3.w, k3.w, d3);
                    sc[t2] = (d0 + d1) + (d2 + d3);
                }
                float mm = fmaxf(fmaxf(fmaxf(sc[0], sc[1]), fmaxf(sc[2], sc[3])), sc[4]);
                float p[5];
                float sum = 0.f;
                #pragma unroll
                for (int t2 = 0; t2 < 5; ++t2) { p[t2] = __expf(sc[t2] - mm); sum += p[t2]; }
                float inv = __builtin_amdgcn_rcpf(sum);
                #pragma unroll
                for (int t2 = 0; t2 < 5; ++t2) p[t2] *= inv;

                #pragma unroll
                for (int r = 0; r < 8; ++r) att[r] = 0.f;
                const float* vr = lds + sel * VSTR + h * 16 + half * 8;
                #pragma unroll 2
                for (int t2 = 0; t2 < 5; ++t2) {
                    float4 v0 = *reinterpret_cast<const float4*>(vr + t2 * 64);
                    float4 v1 = *reinterpret_cast<const float4*>(vr + t2 * 64 + 4);
                    att[0] = fmaf(p[t2], v0.x, att[0]);
                    att[1] = fmaf(p[t2], v0.y, att[1]);
                    att[2] = fmaf(p[t2], v0.z, att[2]);
                    att[3] = fmaf(p[t2], v0.w, att[3]);
                    att[4] = fmaf(p[t2], v1.x, att[4]);
                    att[5] = fmaf(p[t2], v1.y, att[5]);
                    att[6] = fmaf(p[t2], v1.z, att[6]);
                    att[7] = fmaf(p[t2], v1.w, att[7]);
                }
            }
            __syncthreads();   // v reads done; att safe to overwrite v slots

            if (tid < 160) {
                float* ap = lds + sel * VSTR + team * 64 + h * 16 + half * 8;
                *reinterpret_cast<float4*>(ap)     = make_float4(att[0], att[1], att[2], att[3]);
                *reinterpret_cast<float4*>(ap + 4) = make_float4(att[4], att[5], att[6], att[7]);
            }
            if (h < 3) {       // qk (MFMA) for head h+1, phase-local A-frags
                bf16x8 ah[2], al[2];
                build_afrag(lds + H_OFF, l, ah, al);
                #pragma unroll 1
                for (int n = w; n < 10; n += 4) {
                    const int col = n * 16 + cl16;
                    float b = ws[WS_B3QK + (h + 1) * 160 + col];
                    f32x4 acc = {b, b, b, b};
                    acc = mfma_tile(qkfrag + (h + 1) * 2560 + n * 256, ah, al, l, acc);
                    #pragma unroll
                    for (int q = 0; q < 4; ++q)
                        lds[QK_OFF + (r0c + q) * QKSTR + col] = acc[q];
                }
            }
            __syncthreads();
        }

        // ---- S7 (MFMA bf16x3): out[t] = att_t @ W4 + b4 (10 (t,nh) jobs) ----
        #pragma unroll 1
        for (int job = w; job < 10; job += 4) {
            const int t  = job >> 1;         // 0..4
            const int nh = job & 1;          // n-half 0..1
            const int arow  = cl16;
            const int kbase = 8 * (l >> 4);
            bf16x8 ah[2], al[2];
            #pragma unroll
            for (int s = 0; s < 2; ++s) {
                const float* ap = lds + arow * VSTR + t * 64 + 32 * s + kbase;
                float4 f0 = *reinterpret_cast<const float4*>(ap);
                float4 f1 = *reinterpret_cast<const float4*>(ap + 4);
                float fv[8] = {f0.x, f0.y, f0.z, f0.w, f1.x, f1.y, f1.z, f1.w};
                #pragma unroll
                for (int j = 0; j < 8; ++j) {
                    unsigned hb = rnbf16_bits(fv[j]);
                    float fh = __uint_as_float(hb << 16);
                    ah[s][j] = (short)hb;
                    al[s][j] = (short)rnbf16_bits(fv[j] - fh);
                }
            }
            #pragma unroll 1
            for (int i = 0; i < 5; ++i) {
                const int n = nh * 5 + i;
                const int c = n * 16 + cl16;
                float bias = ws[WS_B4 + (c < 151 ? c : 151)];
                f32x4 acc = {bias, bias, bias, bias};
                acc = mfma_tile(wb + n * 256, ah, al, l, acc);
                if (c < 150) {
                    #pragma unroll
                    for (int q = 0; q < 4; ++q)
                        out[(size_t)BATCH * 10 +
                            ((size_t)((e0 + r0c + q) * 5 + st) * 5 + t) * 150 + c] = acc[q];
                }
            }
        }
        __syncthreads();
    }
}

// ---------------------------------------------------------------------------
extern "C" void kernel_launch(void* const* d_in, const int* in_sizes, int n_in,
                              void* d_out, int out_size, void* d_ws, size_t ws_size,
                              hipStream_t stream)
{
    const float* x        = (const float*)d_in[0];
    const float* fc1_w    = (const float*)d_in[1];
    const float* fc1_b    = (const float*)d_in[2];
    const float* fc2_w    = (const float*)d_in[3];
    const float* fc2_b    = (const float*)d_in[4];
    const float* fc3_w    = (const float*)d_in[5];
    const float* fc3_b    = (const float*)d_in[6];
    const float* h0_w     = (const float*)d_in[7];
    const float* h0_b     = (const float*)d_in[8];
    const float* c0_w     = (const float*)d_in[9];
    const float* c0_b     = (const float*)d_in[10];
    // d_in[11] = lstm_wih : unused (LSTM input is all-zeros)
    const float* lstm_whh = (const float*)d_in[12];
    const float* lstm_bih = (const float*)d_in[13];
    const float* lstm_bhh = (const float*)d_in[14];
    const float* predfc_w = (const float*)d_in[15];
    const float* predfc_b = (const float*)d_in[16];
    const float* emb_w    = (const float*)d_in[17];
    const float* emb_b    = (const float*)d_in[18];
    const float* attn_in_w= (const float*)d_in[19];
    const float* attn_in_b= (const float*)d_in[20];
    const float* attn_out_w=(const float*)d_in[21];
    const float* attn_out_b=(const float*)d_in[22];
    const float* unemb_w  = (const float*)d_in[23];
    const float* unemb_b  = (const float*)d_in[24];

    float* ws  = (float*)d_ws;
    float* outp= (float*)d_out;

    k_pre1<<<(PRE1_ITEMS + 255) / 256, 256, 0, stream>>>(
        fc1_w, fc2_w, fc3_w, fc3_b, h0_w, c0_w,
        lstm_whh, lstm_bih, lstm_bhh,
        predfc_w, predfc_b, emb_w, emb_b,
        attn_out_w, attn_out_b, unemb_w, unemb_b, ws);

    k_pre2<<<(PRE2_ITEMS + 255) / 256, 256, 0, stream>>>(attn_in_w, attn_in_b, ws);

    k_pre3<<<40, 256, 0, stream>>>(ws);
    k_pre4<<<304, 256, 0, stream>>>(ws);

    policy_main<<<BATCH / 16, 256, 0, stream>>>(
        x, fc1_b, fc2_b, h0_b, c0_b, ws, outp);
}

// Round 19
// 222.440 us; speedup vs baseline: 1.4879x; 1.0400x over previous
//
#include <hip/hip_runtime.h>

// ---------------------------------------------------------------------------
// PolicyNet fused forward, MFMA bf16x3 step loop, MI355X.
// Round 19: h cached in bf16 hi/lo LDS form. R18 counters: VALUBusy 39% --
// ~500 VALU ops/thread/step re-convert the SAME h to bf16x3 in 5 afrag
// builds. Now: pointwise (and preamble h0) converts once at write; H_HI/H_LO
// ushort[16][72] in LDS; build_afrag = 4x ds_read_b128, zero convert VALU.
// Bit-identical numerics (same rounding path). LDS 40192B -> 4 blocks/CU.
// ---------------------------------------------------------------------------

#define RF(x) __builtin_amdgcn_readfirstlane(x)

constexpr int BATCH = 16384;

typedef short bf16x8 __attribute__((ext_vector_type(8)));
typedef float f32x4  __attribute__((ext_vector_type(4)));

// ---- workspace layout (dwords) ----
constexpr int WS_FC1T = 0;       // [152][64]  fc1_w^T (zero-padded K)
constexpr int WS_FC2T = 9728;    // [64][64]
constexpr int WS_FC3T = 13824;   // [64][12]   (cols 10,11 zero)
constexpr int WS_H0T  = 14592;   // [64][64]
constexpr int WS_C0T  = 18688;   // [64][64]
constexpr int WS_WHHT = 22784;   // [64][256]  whh^T, col = gate*64+j (i,f,g,o)
constexpr int WS_GB   = 39168;   // [256]      bih+bhh
constexpr int WS_W2   = 39424;   // [5][64][64]   emb_w @ predfc_w_t
constexpr int WS_B2   = 59904;   // [5][64]
constexpr int WS_W3QK = 60224;   // [4][64][160]  per head: [k][t*32 + (q0..15|k16..31)]
constexpr int WS_W3V  = 101184;  // [64][320]     [k][t*64 + h*16 + d]
constexpr int WS_B3QK = 121664;  // [4][160]
constexpr int WS_B3V  = 122304;  // [320]
constexpr int WS_W4T  = 122624;  // [64][152]  (unemb_w @ attn_out_w)^T
constexpr int WS_B4   = 132352;  // [152]
constexpr int WS_FC3B = 132504;  // [12]
constexpr int WS_W4F  = 132520;  // [10n][2s][2split][64l][4dw] bf16 B-frags (S7)
constexpr int WS_GF   = 142760;  // gates frags: 16 n-tiles  (16384 dw)
constexpr int WS_VF   = 159144;  // v frags:     20 n-tiles  (20480 dw)
constexpr int WS_QKF  = 179624;  // qk frags: 4 heads x 10 n (40960 dw)
constexpr int WS_TOTAL= 220584;  // dwords (~882 KB)

// ---- LDS layout (dwords), 16-row tile ----
constexpr int VSTR     = 324;    // VBUF [16][324]: gates / v / att (x, h2 alias)
constexpr int QK_OFF   = 5184;   // [16][164]  (h1 aliases)
constexpr int QKSTR    = 164;
constexpr int HHI_OFF  = 7808;   // ushort[16][72] bf16-hi of h  (576 dw)
constexpr int HLO_OFF  = 8384;   // ushort[16][72] bf16-lo of h  (576 dw)
constexpr int HB_STR   = 72;     // ushort stride (row = 144B, 16B-aligned)
constexpr int C_OFF    = 8960;   // [16][68] fp32 c
constexpr int HSTR     = 68;
constexpr int XSTR     = 156;    // x staged at VBUF offset 0
constexpr int H1_OFF   = QK_OFF;
constexpr int H2_OFF   = 2496;   // after x within VBUF
constexpr int LDS_DW   = 10048;  // 40192 bytes -> 4 blocks/CU (4x=160768<=163840)

// ---------------------------------------------------------------------------
__device__ __forceinline__ unsigned rnbf16_bits(float f) {
    unsigned u = __float_as_uint(f);
    return (u + 0x7FFFu + ((u >> 16) & 1u)) >> 16;   // round-nearest-even
}

// ---------------------------------------------------------------------------
// precompute kernel 1: transposes + W2/b2 + W4/b4 + misc biases
// ---------------------------------------------------------------------------
__global__ void k_pre1(const float* __restrict__ fc1_w, const float* __restrict__ fc2_w,
                       const float* __restrict__ fc3_w, const float* __restrict__ fc3_b,
                       const float* __restrict__ h0_w,  const float* __restrict__ c0_w,
                       const float* __restrict__ whh,   const float* __restrict__ bih,
                       const float* __restrict__ bhh,
                       const float* __restrict__ predfc_w, const float* __restrict__ predfc_b,
                       const float* __restrict__ emb_w,    const float* __restrict__ emb_b,
                       const float* __restrict__ aow, const float* __restrict__ aob,
                       const float* __restrict__ unw, const float* __restrict__ unb,
                       float* ws)
{
    int idx = blockIdx.x * 256 + threadIdx.x;
    if (idx < 9728) { int k = idx / 64, c = idx & 63;
        ws[WS_FC1T + idx] = (k < 150) ? fc1_w[c * 150 + k] : 0.f; return; }
    idx -= 9728;
    if (idx < 4096) { int k = idx >> 6, c = idx & 63; ws[WS_FC2T + idx] = fc2_w[c * 64 + k]; return; }
    idx -= 4096;
    if (idx < 768)  { int k = idx / 12, c = idx % 12;
        ws[WS_FC3T + idx] = (c < 10) ? fc3_w[c * 64 + k] : 0.f; return; }
    idx -= 768;
    if (idx < 4096) { int k = idx >> 6, c = idx & 63; ws[WS_H0T + idx] = h0_w[c * 64 + k]; return; }
    idx -= 4096;
    if (idx < 4096) { int k = idx >> 6, c = idx & 63; ws[WS_C0T + idx] = c0_w[c * 64 + k]; return; }
    idx -= 4096;
    if (idx < 16384){ int k = idx >> 8, c = idx & 255; ws[WS_WHHT + idx] = whh[c * 64 + k]; return; }
    idx -= 16384;
    if (idx < 256)  { ws[WS_GB + idx] = bih[idx] + bhh[idx]; return; }
    idx -= 256;
    if (idx < 20480){ int t = idx / 4096, r = idx & 4095, kk = r >> 6, j = r & 63;
        float s = 0.f;
        for (int m = 0; m < 150; ++m)
            s = fmaf(emb_w[kk * 150 + m], predfc_w[(t * 150 + m) * 64 + j], s);
        ws[WS_W2 + idx] = s; return; }
    idx -= 20480;
    if (idx < 320)  { int t = idx / 64, kk = idx & 63;
        float s = emb_b[kk];
        for (int m = 0; m < 150; ++m)
            s = fmaf(emb_w[kk * 150 + m], predfc_b[t * 150 + m], s);
        ws[WS_B2 + idx] = s; return; }
    idx -= 320;
    if (idx < 9728) { int k = idx / 152, ss = idx % 152;
        float v = 0.f;
        if (ss < 150) { float a = 0.f;
            for (int kk = 0; kk < 64; ++kk) a = fmaf(unw[ss * 64 + kk], aow[kk * 64 + k], a);
            v = a; }
        ws[WS_W4T + idx] = v; return; }
    idx -= 9728;
    if (idx < 152)  { float v = 0.f;
        if (idx < 150) { float a = unb[idx];
            for (int kk = 0; kk < 64; ++kk) a = fmaf(unw[idx * 64 + kk], aob[kk], a);
            v = a; }
        ws[WS_B4 + idx] = v; return; }
    idx -= 152;
    if (idx < 12)   { ws[WS_FC3B + idx] = (idx < 10) ? fc3_b[idx] : 0.f; return; }
}
constexpr int PRE1_ITEMS = 70116;

// ---------------------------------------------------------------------------
// precompute kernel 2: W3 = attn_in_w @ W2  (q rows scaled by 0.25), b3
// ---------------------------------------------------------------------------
__global__ void k_pre2(const float* __restrict__ aiw, const float* __restrict__ aib,
                       float* ws)
{
    int idx = blockIdx.x * 256 + threadIdx.x;
    const float* W2 = ws + WS_W2;
    const float* b2 = ws + WS_B2;
    if (idx < 40960) {
        int h = idx / 10240, r = idx % 10240, k = r / 160, c = r % 160;
        int t = c / 32, rr = c % 32;
        int row; float scale;
        if (rr < 16) { row = h * 16 + rr;            scale = 0.25f; }
        else         { row = 64 + h * 16 + (rr - 16); scale = 1.f;  }
        float s = 0.f;
        for (int kk = 0; kk < 64; ++kk)
            s = fmaf(aiw[row * 64 + kk], W2[t * 4096 + kk * 64 + k], s);
        ws[WS_W3QK + idx] = s * scale; return;
    }
    idx -= 40960;
    if (idx < 20480) {
        int k = idx / 320, c = idx % 320, t = c >> 6, r3 = c & 63;
        int row = 128 + r3;
        float s = 0.f;
        for (int kk = 0; kk < 64; ++kk)
            s = fmaf(aiw[row * 64 + kk], W2[t * 4096 + kk * 64 + k], s);
        ws[WS_W3V + idx] = s; return;
    }
    idx -= 20480;
    if (idx < 640) {
        int h = idx / 160, c = idx % 160, t = c / 32, rr = c % 32;
        int row; float scale;
        if (rr < 16) { row = h * 16 + rr;            scale = 0.25f; }
        else         { row = 64 + h * 16 + (rr - 16); scale = 1.f;  }
        float s = aib[row];
        for (int kk = 0; kk < 64; ++kk)
            s = fmaf(aiw[row * 64 + kk], b2[t * 64 + kk], s);
        ws[WS_B3QK + idx] = s * scale; return;
    }
    idx -= 640;
    if (idx < 320) {
        int t = idx >> 6, r3 = idx & 63, row = 128 + r3;
        float s = aib[row];
        for (int kk = 0; kk < 64; ++kk)
            s = fmaf(aiw[row * 64 + kk], b2[t * 64 + kk], s);
        ws[WS_B3V + idx] = s; return;
    }
}
constexpr int PRE2_ITEMS = 62400;

// ---------------------------------------------------------------------------
// precompute kernel 3: W4 bf16 hi/lo B-fragment pack (validated R4).
// ---------------------------------------------------------------------------
__global__ void k_pre3(float* ws)
{
    int idx = blockIdx.x * 256 + threadIdx.x;   // 10240 dwords
    if (idx >= 10240) return;
    int j2 = idx & 3, l = (idx >> 2) & 63, r = idx >> 8;
    int split = r & 1, s = (r >> 1) & 1, n = r >> 2;
    int col = 16 * n + (l & 15);
    unsigned bits[2];
    #pragma unroll
    for (int q = 0; q < 2; ++q) {
        int k = 32 * s + 8 * (l >> 4) + 2 * j2 + q;
        float v = (col < 152) ? ws[WS_W4T + k * 152 + col] : 0.f;
        unsigned hb = rnbf16_bits(v);
        if (split == 0) bits[q] = hb;
        else {
            float fh = __uint_as_float(hb << 16);
            bits[q] = rnbf16_bits(v - fh);
        }
    }
    reinterpret_cast<unsigned*>(ws)[WS_W4F + idx] = bits[0] | (bits[1] << 16);
}

// ---------------------------------------------------------------------------
// precompute kernel 4: pack WHH / W3V / W3QK into B-fragment order.
// ---------------------------------------------------------------------------
__global__ void k_pre4(float* ws)
{
    int idx = blockIdx.x * 256 + threadIdx.x;
    if (idx >= 77824) return;
    const float* src; int N, rel, dst;
    if (idx < 16384)      { src = ws + WS_WHHT; N = 256; rel = idx;         dst = WS_GF + idx; }
    else if (idx < 36864) { src = ws + WS_W3V;  N = 320; rel = idx - 16384; dst = WS_VF + rel; }
    else {
        int r = idx - 36864;
        int h = r / 10240;  rel = r % 10240;
        src = ws + WS_W3QK + h * 10240; N = 160;
        dst = WS_QKF + r;
    }
    int n = rel >> 10, sub = rel & 1023;
    int s = sub >> 9, split = (sub >> 8) & 1, lj = sub & 255;
    int l = lj >> 2, j2 = lj & 3;
    int col = n * 16 + (l & 15);
    unsigned bits[2];
    #pragma unroll
    for (int q = 0; q < 2; ++q) {
        int k = 32 * s + 8 * (l >> 4) + 2 * j2 + q;
        float v = src[k * N + col];
        unsigned hb = rnbf16_bits(v);
        if (split == 0) bits[q] = hb;
        else bits[q] = rnbf16_bits(v - __uint_as_float(hb << 16));
    }
    reinterpret_cast<unsigned*>(ws)[dst] = bits[0] | (bits[1] << 16);
}

// ---------------------------------------------------------------------------
// helpers
// ---------------------------------------------------------------------------
__device__ __forceinline__ float sigf(float v) {
    return __builtin_amdgcn_rcpf(1.f + __expf(-v));
}
__device__ __forceinline__ float tanh_fast(float v) {
    float e = __expf(-2.f * v);
    return fmaf(-2.f, e * __builtin_amdgcn_rcpf(1.f + e), 1.f);   // (1-e)/(1+e)
}

// fp32 kloop (preamble only)
template<int NC, int K, int WS>
__device__ __forceinline__ void kloop(const float* __restrict__ wT,
                                      const float* __restrict__ a_row,
                                      float* acc)
{
    #pragma unroll 4
    for (int k = 0; k < K; k += 4) {
        const float4 av = *reinterpret_cast<const float4*>(a_row + k);
        const float* wr = wT + k * WS;
        #pragma unroll
        for (int c = 0; c < NC; ++c) acc[c] = fmaf(av.x, wr[c], acc[c]);
        #pragma unroll
        for (int c = 0; c < NC; ++c) acc[c] = fmaf(av.y, wr[WS + c], acc[c]);
        #pragma unroll
        for (int c = 0; c < NC; ++c) acc[c] = fmaf(av.z, wr[2 * WS + c], acc[c]);
        #pragma unroll
        for (int c = 0; c < NC; ++c) acc[c] = fmaf(av.w, wr[3 * WS + c], acc[c]);
    }
}

// one 16x16 output tile, K=64, bf16x3: 6 MFMA. base = frag ptr for this n-tile.
__device__ __forceinline__ f32x4 mfma_tile(const bf16x8* __restrict__ base,
                                           const bf16x8* ah, const bf16x8* al,
                                           int l, f32x4 acc)
{
    #pragma unroll
    for (int s = 0; s < 2; ++s) {
        bf16x8 bh = base[s * 128 + l];
        bf16x8 bl = base[s * 128 + 64 + l];
        acc = __builtin_amdgcn_mfma_f32_16x16x32_bf16(al[s], bh, acc, 0, 0, 0);
        acc = __builtin_amdgcn_mfma_f32_16x16x32_bf16(ah[s], bl, acc, 0, 0, 0);
        acc = __builtin_amdgcn_mfma_f32_16x16x32_bf16(ah[s], bh, acc, 0, 0, 0);
    }
    return acc;
}

// A-frags from pre-converted bf16 hi/lo LDS arrays: 4x ds_read_b128, no VALU
__device__ __forceinline__ void build_afrag_bf(const unsigned short* __restrict__ hhi,
                                               const unsigned short* __restrict__ hlo,
                                               int l, bf16x8* ah, bf16x8* al)
{
    const int off = (l & 15) * HB_STR + 8 * (l >> 4);
    #pragma unroll
    for (int s = 0; s < 2; ++s) {
        ah[s] = *reinterpret_cast<const bf16x8*>(hhi + off + 32 * s);
        al[s] = *reinterpret_cast<const bf16x8*>(hlo + off + 32 * s);
    }
}

// ---------------------------------------------------------------------------
// main fused kernel: 1 block = 16 batch elements, 256 threads = 4 waves
// ---------------------------------------------------------------------------
__global__ void __launch_bounds__(256, 2)
policy_main(const float* __restrict__ x,
            const float* __restrict__ fc1_b, const float* __restrict__ fc2_b,
            const float* __restrict__ h0_b,  const float* __restrict__ c0_b,
            const float* __restrict__ ws,    float* __restrict__ out)
{
    __shared__ float lds[LDS_DW];
    unsigned short* hhi = reinterpret_cast<unsigned short*>(lds + HHI_OFF);
    unsigned short* hlo = reinterpret_cast<unsigned short*>(lds + HLO_OFF);

    const int tid = threadIdx.x;
    const int l   = tid & 63;
    const int w   = RF(tid >> 6);            // 0..3
    const int el  = l & 15;                  // element within tile (preamble)
    const int q4  = l >> 4;                  // quarter 0..3 (preamble cols)
    const int e0  = blockIdx.x * 16;
    const int r0c = (l >> 4) << 2;           // C-fragment row base
    const int cl16 = l & 15;

    // ---- stage x tile (zero-pad cols 150..155) ----
    for (int idx = tid; idx < 16 * XSTR; idx += 256) {
        int r = idx / XSTR, k = idx - r * XSTR;
        lds[idx] = (k < 150) ? x[(e0 + r) * 150 + k] : 0.f;
    }
    __syncthreads();

    // ---- fc1 -> h1 (relu) : 4 waves x 4 quarters x 4 cols ----
    {
        const int c0 = w * 16 + q4 * 4;
        float acc[4];
        #pragma unroll
        for (int c = 0; c < 4; ++c) acc[c] = fc1_b[c0 + c];
        kloop<4, 152, 64>(ws + WS_FC1T + c0, lds + el * XSTR, acc);
        float* hp = lds + H1_OFF + el * HSTR + c0;
        *reinterpret_cast<float4*>(hp) =
            make_float4(fmaxf(acc[0],0.f), fmaxf(acc[1],0.f), fmaxf(acc[2],0.f), fmaxf(acc[3],0.f));
    }
    __syncthreads();

    // ---- fc2 -> h2 (relu) ----
    {
        const int c0 = w * 16 + q4 * 4;
        float acc[4];
        #pragma unroll
        for (int c = 0; c < 4; ++c) acc[c] = fc2_b[c0 + c];
        kloop<4, 64, 64>(ws + WS_FC2T + c0, lds + H1_OFF + el * HSTR, acc);
        float* hp = lds + H2_OFF + el * HSTR + c0;
        *reinterpret_cast<float4*>(hp) =
            make_float4(fmaxf(acc[0],0.f), fmaxf(acc[1],0.f), fmaxf(acc[2],0.f), fmaxf(acc[3],0.f));
    }
    __syncthreads();

    // ---- h0 (bf16 hi/lo), c0 (fp32) + fc3 softmax (wave0/q4==0) ----
    for (int j = w; j < 16; j += 4) {
        const int  cc  = (j & 7) * 8 + q4 * 2;
        const bool isC = (j >= 8);
        const float* wT = ws + (isC ? WS_C0T : WS_H0T) + cc;
        const float* bb = isC ? c0_b : h0_b;
        float acc[2];
        #pragma unroll
        for (int c = 0; c < 2; ++c) acc[c] = bb[cc + c];
        kloop<2, 64, 64>(wT, lds + H2_OFF + el * HSTR, acc);
        if (isC) {
            float* dp = lds + C_OFF + el * HSTR + cc;
            *reinterpret_cast<float2*>(dp) = make_float2(acc[0], acc[1]);
        } else {
            unsigned short* hh = hhi + el * HB_STR + cc;
            unsigned short* hl = hlo + el * HB_STR + cc;
            #pragma unroll
            for (int c = 0; c < 2; ++c) {
                unsigned hb = rnbf16_bits(acc[c]);
                hh[c] = (unsigned short)hb;
                hl[c] = (unsigned short)rnbf16_bits(acc[c] - __uint_as_float(hb << 16));
            }
        }
    }
    if (w == 0 && q4 == 0) {
        float acc[12];
        #pragma unroll
        for (int c = 0; c < 12; ++c) acc[c] = ws[WS_FC3B + c];
        kloop<12, 64, 12>(ws + WS_FC3T, lds + H2_OFF + el * HSTR, acc);
        float mm = acc[0];
        #pragma unroll
        for (int i = 1; i < 10; ++i) mm = fmaxf(mm, acc[i]);
        float sum = 0.f;
        #pragma unroll
        for (int i = 0; i < 10; ++i) { acc[i] = __expf(acc[i] - mm); sum += acc[i]; }
        float inv = __builtin_amdgcn_rcpf(sum);
        float* op = out + (size_t)(e0 + el) * 10;
        #pragma unroll
        for (int i = 0; i < 10; i += 2)
            *reinterpret_cast<float2*>(op + i) = make_float2(acc[i] * inv, acc[i + 1] * inv);
    }
    __syncthreads();

    const bf16x8* gfrag  = reinterpret_cast<const bf16x8*>(ws + WS_GF);
    const bf16x8* vfrag  = reinterpret_cast<const bf16x8*>(ws + WS_VF);
    const bf16x8* qkfrag = reinterpret_cast<const bf16x8*>(ws + WS_QKF);
    const bf16x8* wb     = reinterpret_cast<const bf16x8*>(ws + WS_W4F);

    // score-phase thread mapping: tid<160, grp 0..9, team 0..4, half 0..1
    const int grp  = tid >> 4;
    const int sel  = tid & 15;
    const int team = (grp < 5) ? grp : grp - 5;
    const int half = (grp < 5) ? 0 : 1;

    // ================== LSTM / attention steps ==================
    #pragma unroll 1
    for (int st = 0; st < 5; ++st) {
        // ---- S1a (MFMA): gates = h @ whh^T + gb : wave -> 4 n-tiles ----
        {
            bf16x8 ah[2], al[2];
            build_afrag_bf(hhi, hlo, l, ah, al);
            #pragma unroll 1
            for (int i = 0; i < 4; ++i) {
                const int n   = w * 4 + i;
                const int col = n * 16 + cl16;
                float b = ws[WS_GB + col];
                f32x4 acc = {b, b, b, b};
                acc = mfma_tile(gfrag + n * 256, ah, al, l, acc);
                #pragma unroll
                for (int q = 0; q < 4; ++q)
                    lds[(r0c + q) * VSTR + col] = acc[q];
            }
        }
        __syncthreads();

        // ---- S1b: LSTM pointwise; h written as bf16 hi/lo ----
        {
            const int ee = tid & 15;
            const int j0 = (tid >> 4) * 4;
            const float* gr = lds + ee * VSTR;
            float* cr = lds + C_OFF + ee * HSTR;
            float4 ig = *reinterpret_cast<const float4*>(gr + j0);
            float4 fg = *reinterpret_cast<const float4*>(gr + 64 + j0);
            float4 gg = *reinterpret_cast<const float4*>(gr + 128 + j0);
            float4 og = *reinterpret_cast<const float4*>(gr + 192 + j0);
            float4 cv = *reinterpret_cast<const float4*>(cr + j0);
            float cn[4];
            unsigned hh[4], hl[4];
            #pragma unroll
            for (int q = 0; q < 4; ++q) {
                float iv = (&ig.x)[q], fv = (&fg.x)[q], gv = (&gg.x)[q],
                      ov = (&og.x)[q], c_ = (&cv.x)[q];
                float cc = sigf(fv) * c_ + sigf(iv) * tanh_fast(gv);
                cn[q] = cc;
                float hn = sigf(ov) * tanh_fast(cc);
                unsigned hb = rnbf16_bits(hn);
                hh[q] = hb;
                hl[q] = rnbf16_bits(hn - __uint_as_float(hb << 16));
            }
            *reinterpret_cast<float4*>(cr + j0) = make_float4(cn[0], cn[1], cn[2], cn[3]);
            uint2 ph = { hh[0] | (hh[1] << 16), hh[2] | (hh[3] << 16) };
            uint2 pl = { hl[0] | (hl[1] << 16), hl[2] | (hl[3] << 16) };
            *reinterpret_cast<uint2*>(hhi + ee * HB_STR + j0) = ph;
            *reinterpret_cast<uint2*>(hlo + ee * HB_STR + j0) = pl;
        }
        __syncthreads();

        // ---- S2: v (5 tiles) + qk head0 ----
        {
            bf16x8 ah[2], al[2];
            build_afrag_bf(hhi, hlo, l, ah, al);
            #pragma unroll 1
            for (int i = 0; i < 5; ++i) {
                const int n   = w * 5 + i;
                const int col = n * 16 + cl16;
                float b = ws[WS_B3V + col];
                f32x4 acc = {b, b, b, b};
                acc = mfma_tile(vfrag + n * 256, ah, al, l, acc);
                #pragma unroll
                for (int q = 0; q < 4; ++q)
                    lds[(r0c + q) * VSTR + col] = acc[q];
            }
            #pragma unroll 1
            for (int n = w; n < 10; n += 4) {
                const int col = n * 16 + cl16;
                float b = ws[WS_B3QK + col];
                f32x4 acc = {b, b, b, b};
                acc = mfma_tile(qkfrag + n * 256, ah, al, l, acc);
                #pragma unroll
                for (int q = 0; q < 4; ++q)
                    lds[QK_OFF + (r0c + q) * QKSTR + col] = acc[q];
            }
        }
        __syncthreads();

        // ---- per-head: scores+softmax+PV(half) | att-write + next qk ----
        float att[8];
        #pragma unroll 1
        for (int h = 0; h < 4; ++h) {
            if (tid < 160) {
                const float* qk = lds + QK_OFF + sel * QKSTR;
                float4 q0 = *reinterpret_cast<const float4*>(qk + team * 32);
                float4 q1 = *reinterpret_cast<const float4*>(qk + team * 32 + 4);
                float4 q2 = *reinterpret_cast<const float4*>(qk + team * 32 + 8);
                float4 q3 = *reinterpret_cast<const float4*>(qk + team * 32 + 12);
                float sc[5];
                #pragma unroll 2
                for (int t2 = 0; t2 < 5; ++t2) {
                    const float* kp = qk + t2 * 32 + 16;
                    float4 k0 = *reinterpret_cast<const float4*>(kp);
                    float4 k1 = *reinterpret_cast<const float4*>(kp + 4);
                    float4 k2 = *reinterpret_cast<const float4*>(kp + 8);
                    float4 k3 = *reinterpret_cast<const float4*>(kp + 12);
                    float d0 = q0.x * k0.x; d0 = fmaf(q0.y, k0.y, d0); d0 = fmaf(q0.z, k0.z, d0); d0 = fmaf(q0.w, k0.w, d0);
                    float d1 = q1.x * k1.x; d1 = fmaf(q1.y, k1.y, d1); d1 = fmaf(q1.z, k1.z, d1); d1 = fmaf(q1.w, k1.w, d1);
                    float d2 = q2.x * k2.x; d2 = fmaf(q2.y, k2.y, d2); d2 = fmaf(q2.z, k2.z, d2); d2 = fmaf(q2.w, k2.w, d2);
                    float d3 = q3.x * k3.x; d3 = fmaf(q3.y, k3.y, d3); d3 = fmaf(q3.z, k3.z, d3); d3 = fmaf(q3.w, k3.w, d3);
                    sc[t2] = (d0 + d1) + (d2 + d3);
                }
                float mm = fmaxf(fmaxf(fmaxf(sc[0], sc[1]), fmaxf(sc[2], sc[3])), sc[4]);
                float p[5];
                float sum = 0.f;
                #pragma unroll
                for (int t2 = 0; t2 < 5; ++t2) { p[t2] = __expf(sc[t2] - mm); sum += p[t2]; }
                float inv = __builtin_amdgcn_rcpf(sum);
                #pragma unroll
                for (int t2 = 0; t2 < 5; ++t2) p[t2] *= inv;

                #pragma unroll
                for (int r = 0; r < 8; ++r) att[r] = 0.f;
                const float* vr = lds + sel * VSTR + h * 16 + half * 8;
                #pragma unroll 2
                for (int t2 = 0; t2 < 5; ++t2) {
                    float4 v0 = *reinterpret_cast<const float4*>(vr + t2 * 64);
                    float4 v1 = *reinterpret_cast<const float4*>(vr + t2 * 64 + 4);
                    att[0] = fmaf(p[t2], v0.x, att[0]);
                    att[1] = fmaf(p[t2], v0.y, att[1]);
                    att[2] = fmaf(p[t2], v0.z, att[2]);
                    att[3] = fmaf(p[t2], v0.w, att[3]);
                    att[4] = fmaf(p[t2], v1.x, att[4]);
                    att[5] = fmaf(p[t2], v1.y, att[5]);
                    att[6] = fmaf(p[t2], v1.z, att[6]);
                    att[7] = fmaf(p[t2], v1.w, att[7]);
                }
            }
            __syncthreads();   // v reads done; att safe to overwrite v slots

            if (tid < 160) {
                float* ap = lds + sel * VSTR + team * 64 + h * 16 + half * 8;
                *reinterpret_cast<float4*>(ap)     = make_float4(att[0], att[1], att[2], att[3]);
                *reinterpret_cast<float4*>(ap + 4) = make_float4(att[4], att[5], att[6], att[7]);
            }
            if (h < 3) {       // qk (MFMA) for head h+1
                bf16x8 ah[2], al[2];
                build_afrag_bf(hhi, hlo, l, ah, al);
                #pragma unroll 1
                for (int n = w; n < 10; n += 4) {
                    const int col = n * 16 + cl16;
                    float b = ws[WS_B3QK + (h + 1) * 160 + col];
                    f32x4 acc = {b, b, b, b};
                    acc = mfma_tile(qkfrag + (h + 1) * 2560 + n * 256, ah, al, l, acc);
                    #pragma unroll
                    for (int q = 0; q < 4; ++q)
                        lds[QK_OFF + (r0c + q) * QKSTR + col] = acc[q];
                }
            }
            __syncthreads();
        }

        // ---- S7 (MFMA bf16x3): out[t] = att_t @ W4 + b4 (10 (t,nh) jobs) ----
        #pragma unroll 1
        for (int job = w; job < 10; job += 4) {
            const int t  = job >> 1;         // 0..4
            const int nh = job & 1;          // n-half 0..1
            const int arow  = cl16;
            const int kbase = 8 * (l >> 4);
            bf16x8 ah[2], al[2];
            #pragma unroll
            for (int s = 0; s < 2; ++s) {
                const float* ap = lds + arow * VSTR + t * 64 + 32 * s + kbase;
                float4 f0 = *reinterpret_cast<const float4*>(ap);
                float4 f1 = *reinterpret_cast<const float4*>(ap + 4);
                float fv[8] = {f0.x, f0.y, f0.z, f0.w, f1.x, f1.y, f1.z, f1.w};
                #pragma unroll
                for (int j = 0; j < 8; ++j) {
                    unsigned hb = rnbf16_bits(fv[j]);
                    float fh = __uint_as_float(hb << 16);
                    ah[s][j] = (short)hb;
                    al[s][j] = (short)rnbf16_bits(fv[j] - fh);
                }
            }
            #pragma unroll 1
            for (int i = 0; i < 5; ++i) {
                const int n = nh * 5 + i;
                const int c = n * 16 + cl16;
                float bias = ws[WS_B4 + (c < 151 ? c : 151)];
                f32x4 acc = {bias, bias, bias, bias};
                acc = mfma_tile(wb + n * 256, ah, al, l, acc);
                if (c < 150) {
                    #pragma unroll
                    for (int q = 0; q < 4; ++q)
                        out[(size_t)BATCH * 10 +
                            ((size_t)((e0 + r0c + q) * 5 + st) * 5 + t) * 150 + c] = acc[q];
                }
            }
        }
        __syncthreads();
    }
}

// ---------------------------------------------------------------------------
extern "C" void kernel_launch(void* const* d_in, const int* in_sizes, int n_in,
                              void* d_out, int out_size, void* d_ws, size_t ws_size,
                              hipStream_t stream)
{
    const float* x        = (const float*)d_in[0];
    const float* fc1_w    = (const float*)d_in[1];
    const float* fc1_b    = (const float*)d_in[2];
    const float* fc2_w    = (const float*)d_in[3];
    const float* fc2_b    = (const float*)d_in[4];
    const float* fc3_w    = (const float*)d_in[5];
    const float* fc3_b    = (const float*)d_in[6];
    const float* h0_w     = (const float*)d_in[7];
    const float* h0_b     = (const float*)d_in[8];
    const float* c0_w     = (const float*)d_in[9];
    const float* c0_b     = (const float*)d_in[10];
    // d_in[11] = lstm_wih : unused (LSTM input is all-zeros)
    const float* lstm_whh = (const float*)d_in[12];
    const float* lstm_bih = (const float*)d_in[13];
    const float* lstm_bhh = (const float*)d_in[14];
    const float* predfc_w = (const float*)d_in[15];
    const float* predfc_b = (const float*)d_in[16];
    const float* emb_w    = (const float*)d_in[17];
    const float* emb_b    = (const float*)d_in[18];
    const float* attn_in_w= (const float*)d_in[19];
    const float* attn_in_b= (const float*)d_in[20];
    const float* attn_out_w=(const float*)d_in[21];
    const float* attn_out_b=(const float*)d_in[22];
    const float* unemb_w  = (const float*)d_in[23];
    const float* unemb_b  = (const float*)d_in[24];

    float* ws  = (float*)d_ws;
    float* outp= (float*)d_out;

    k_pre1<<<(PRE1_ITEMS + 255) / 256, 256, 0, stream>>>(
        fc1_w, fc2_w, fc3_w, fc3_b, h0_w, c0_w,
        lstm_whh, lstm_bih, lstm_bhh,
        predfc_w, predfc_b, emb_w, emb_b,
        attn_out_w, attn_out_b, unemb_w, unemb_b, ws);

    k_pre2<<<(PRE2_ITEMS + 255) / 256, 256, 0, stream>>>(attn_in_w, attn_in_b, ws);

    k_pre3<<<40, 256, 0, stream>>>(ws);
    k_pre4<<<304, 256, 0, stream>>>(ws);

    policy_main<<<BATCH / 16, 256, 0, stream>>>(
        x, fc1_b, fc2_b, h0_b, c0_b, ws, outp);
}